// Round 14
// baseline (302.584 us; speedup 1.0000x reference)
//
#include <hip/hip_runtime.h>
#include <math.h>

#define EPSV 1e-5f
#define SCALE_W 0.0441941738241592f   /* 1/sqrt(512) */
#define GAIN_R 1.4142135623730951f    /* sqrt(2) */

typedef __attribute__((ext_vector_type(8))) short bf16x8;
typedef __attribute__((ext_vector_type(4))) float f32x4;
typedef __attribute__((ext_vector_type(4))) unsigned int u32x4;

static __device__ __forceinline__ unsigned short f2bf(float f) {
  union { float f; unsigned int u; } v; v.f = f;
  unsigned int r = v.u + 0x7FFFu + ((v.u >> 16) & 1u);   // RNE
  return (unsigned short)(r >> 16);
}

// packed f32->bf16 (RNE): lo -> low16, hi -> high16
static __device__ __forceinline__ unsigned int cvtpk(float lo, float hi) {
  unsigned int r;
  asm("v_cvt_pk_bf16_f32 %0, %1, %2" : "=v"(r) : "v"(lo), "v"(hi));
  return r;
}

// ---------------- pre-kernel: b = expmap0(bias), y2 = ||b||^2 ----------------
__global__ void bias_expmap_k(const float* __restrict__ bias, float* __restrict__ bexp,
                              float* __restrict__ y2out) {
  __shared__ float part[8];
  int t = threadIdx.x;
  float bv = bias[t];
  float s = bv * bv;
  s += __shfl_xor(s, 1);  s += __shfl_xor(s, 2);  s += __shfl_xor(s, 4);
  s += __shfl_xor(s, 8);  s += __shfl_xor(s, 16); s += __shfl_xor(s, 32);
  if ((t & 63) == 0) part[t >> 6] = s;
  __syncthreads();
  float tot = 0.f;
#pragma unroll
  for (int i = 0; i < 8; ++i) tot += part[i];
  float un = fmaxf(sqrtf(tot), EPSV);
  float th = tanhf(un);
  bexp[t] = th * bv / un;
  if (t == 0) *y2out = th * th;
}

// ---------------- pre-kernel: pack weight -> bf16 A-fragments, SCALE baked ----
// chunk (ks*32 + colhi): lane (lgr*16+l15) holds W[col=colhi*16+l15][k=ks*32+lgr*8+j].
__global__ void pack_weight_k(const float* __restrict__ w, unsigned short* __restrict__ wsB) {
  int e = blockIdx.x * 256 + threadIdx.x;   // 0..262143
  int o = e >> 9;          // output col (row of W)
  int k = e & 511;
  int ks = k >> 5, kk = k & 31;
  int lgr = kk >> 3, j = kk & 7;
  int colhi = o >> 4, l15 = o & 15;
  int dst = ((ks * 32 + colhi) * 64 + lgr * 16 + l15) * 8 + j;
  wsB[dst] = f2bf(w[e] * SCALE_W);
}

// ---------------- main kernel: free-running waves, no barriers, no LDS ----------------
// Each wave owns 16 x-rows x 512 cols. Lane (l15,lgr): row l15, k-slice lgr*8..+7.
// Per K-step (32 k): 32 W-fragments (4 batches of 8, 2 reg banks) + 1 x fragment.
// acc[nf][j] = out[row=chunk*16+l15][col = nf*16 + lgr*4 + j].
__global__ __launch_bounds__(256)
void hyp_free_k(const float* __restrict__ x, const unsigned short* __restrict__ wsB,
                const float* __restrict__ bexp, const float* __restrict__ y2p,
                float* __restrict__ out) {
  const int lane = threadIdx.x & 63;
  const int wave = threadIdx.x >> 6;
  const int l15  = lane & 15;
  const int lgr  = lane >> 4;
  const int wid  = ((blockIdx.x & 7) << 8) + (blockIdx.x >> 3);  // XCD-chunked (2048=8*256)
  const long chunk = (long)wid * 4 + wave;
  const long row   = chunk * 16 + l15;
  const float* xr  = x + row * 512 + lgr * 8;            // + t*32 per step
  const char*  wb  = (const char*)wsB + lane * 16;       // + (t*32+nf)*1024

  const float y2v = *y2p;

  f32x4 acc[32];
#pragma unroll
  for (int nf = 0; nf < 32; ++nf) acc[nf] = f32x4{0.f, 0.f, 0.f, 0.f};

  f32x4 xraw[2][2];      // raw x(t) in bank t&1
  u32x4 xf[2];           // converted bf16 fragment of x(t) in bank t&1
  bf16x8 wfA[8], wfB[8]; // W fragment ping-pong banks
  float xss = 0.f;

  // ---- prologue: x(0)->bank0, x(1)->bank1; convert x(0) ----
  xraw[0][0] = __builtin_nontemporal_load((const f32x4*)xr);
  xraw[0][1] = __builtin_nontemporal_load((const f32x4*)(xr + 4));
  xraw[1][0] = __builtin_nontemporal_load((const f32x4*)(xr + 32));
  xraw[1][1] = __builtin_nontemporal_load((const f32x4*)(xr + 36));
  {
    f32x4 a = xraw[0][0], b = xraw[0][1];
    xss += a[0]*a[0] + a[1]*a[1] + a[2]*a[2] + a[3]*a[3];
    xss += b[0]*b[0] + b[1]*b[1] + b[2]*b[2] + b[3]*b[3];
    xf[0][0] = cvtpk(a[0], a[1]); xf[0][1] = cvtpk(a[2], a[3]);
    xf[0][2] = cvtpk(b[0], b[1]); xf[0][3] = cvtpk(b[2], b[3]);
  }

#pragma unroll 2
  for (int t = 0; t < 16; ++t) {
    const int p = t & 1, q = p ^ 1;
    const char* wbt = wb + (size_t)t * 32768;
    const bf16x8 xfv = __builtin_bit_cast(bf16x8, xf[p]);

    // batch0 -> wfA
#pragma unroll
    for (int i = 0; i < 8; ++i) wfA[i] = *(const bf16x8*)(wbt + i * 1024);
    // convert x(t+1) (loaded last step) while batch0 flies
    if (t < 15) {
      f32x4 a = xraw[q][0], b = xraw[q][1];
      xss += a[0]*a[0] + a[1]*a[1] + a[2]*a[2] + a[3]*a[3];
      xss += b[0]*b[0] + b[1]*b[1] + b[2]*b[2] + b[3]*b[3];
      xf[q][0] = cvtpk(a[0], a[1]); xf[q][1] = cvtpk(a[2], a[3]);
      xf[q][2] = cvtpk(b[0], b[1]); xf[q][3] = cvtpk(b[2], b[3]);
    }
    // batch1 -> wfB
#pragma unroll
    for (int i = 0; i < 8; ++i) wfB[i] = *(const bf16x8*)(wbt + (8 + i) * 1024);
    // mfma batch0
#pragma unroll
    for (int i = 0; i < 8; ++i)
      acc[i] = __builtin_amdgcn_mfma_f32_16x16x32_bf16(wfA[i], xfv, acc[i], 0, 0, 0);
    // batch2 -> wfA (WAR-safe: prior MFMAs read at issue)
#pragma unroll
    for (int i = 0; i < 8; ++i) wfA[i] = *(const bf16x8*)(wbt + (16 + i) * 1024);
    // mfma batch1
#pragma unroll
    for (int i = 0; i < 8; ++i)
      acc[8 + i] = __builtin_amdgcn_mfma_f32_16x16x32_bf16(wfB[i], xfv, acc[8 + i], 0, 0, 0);
    // batch3 -> wfB
#pragma unroll
    for (int i = 0; i < 8; ++i) wfB[i] = *(const bf16x8*)(wbt + (24 + i) * 1024);
    // issue x(t+2) into freed bank p
    if (t < 14) {
      const float* pn = xr + (t + 2) * 32;
      xraw[p][0] = __builtin_nontemporal_load((const f32x4*)pn);
      xraw[p][1] = __builtin_nontemporal_load((const f32x4*)(pn + 4));
    }
    // mfma batch2, batch3
#pragma unroll
    for (int i = 0; i < 8; ++i)
      acc[16 + i] = __builtin_amdgcn_mfma_f32_16x16x32_bf16(wfA[i], xfv, acc[16 + i], 0, 0, 0);
#pragma unroll
    for (int i = 0; i < 8; ++i)
      acc[24 + i] = __builtin_amdgcn_mfma_f32_16x16x32_bf16(wfB[i], xfv, acc[24 + i], 0, 0, 0);
  }

  // ---- wave-local hyperbolic epilogue (no LDS; shfl_xor 16/32 reductions) ----
  float S2 = 0.f, SB = 0.f;
#pragma unroll
  for (int nf = 0; nf < 32; ++nf) {
    f32x4 bv = *(const f32x4*)(bexp + nf * 16 + lgr * 4);
#pragma unroll
    for (int j = 0; j < 4; ++j) {
      float v = acc[nf][j];
      S2 += v * v;
      SB += v * bv[j];
    }
  }
  S2 += __shfl_xor(S2, 16); S2 += __shfl_xor(S2, 32);
  SB += __shfl_xor(SB, 16); SB += __shfl_xor(SB, 32);
  float xs = xss;
  xs += __shfl_xor(xs, 16); xs += __shfl_xor(xs, 32);

  // per-row scalars (redundant across the 4 lgr lanes of this row — uniform, no divergence)
  float g1, g2;
  {
    float xn  = fmaxf(sqrtf(xs), EPSV);
    float mxn = fmaxf(sqrtf(S2), EPSV);
    float f = tanhf((mxn / xn) * atanhf(fminf(xn, 1.f - EPSV))) / mxn;  // mv = f*mx
    float xy = f * SB;
    float x2 = f * f * S2;
    float den = 1.f + 2.f * xy + x2 * y2v + EPSV;
    g1 = (1.f + 2.f * xy + y2v) * f / den;   // coeff on mx
    g2 = (1.f - x2) / den;                   // coeff on b
    float n1sq = g1 * g1 * S2 + 2.f * g1 * g2 * SB + g2 * g2 * y2v;
    float n1 = fmaxf(sqrtf(fmaxf(n1sq, 0.f)), EPSV);
    if (n1 > 0.999f) { float sc = 0.999f / n1; g1 *= sc; g2 *= sc; }   // project()
  }

  // pass 2: v = lrelu(g1*mx + g2*b); ||v||^2
  float n2 = 0.f;
#pragma unroll
  for (int nf = 0; nf < 32; ++nf) {
    f32x4 bv = *(const f32x4*)(bexp + nf * 16 + lgr * 4);
#pragma unroll
    for (int j = 0; j < 4; ++j) {
      float v = g1 * acc[nf][j] + g2 * bv[j];
      v = v > 0.f ? v : 0.2f * v;
      acc[nf][j] = v;
      n2 += v * v;
    }
  }
  n2 += __shfl_xor(n2, 16); n2 += __shfl_xor(n2, 32);
  float nn = fmaxf(sqrtf(n2), EPSV);
  float tml = tanhf(GAIN_R * atanhf(fminf(nn, 1.f - EPSV))) / nn;

  // store: row-local, 32 x 16B nt stores
  float* orow = out + row * 512 + lgr * 4;
#pragma unroll
  for (int nf = 0; nf < 32; ++nf) {
    f32x4 o = acc[nf];
    o[0] *= tml; o[1] *= tml; o[2] *= tml; o[3] *= tml;
    __builtin_nontemporal_store(o, (f32x4*)(orow + nf * 16));
  }
}

extern "C" void kernel_launch(void* const* d_in, const int* in_sizes, int n_in,
                              void* d_out, int out_size, void* d_ws, size_t ws_size,
                              hipStream_t stream) {
  const float* x    = (const float*)d_in[0];
  const float* w    = (const float*)d_in[1];
  const float* bias = (const float*)d_in[2];
  float* out = (float*)d_out;

  unsigned short* wsB = (unsigned short*)d_ws;                 // 524288 B
  float* bexp = (float*)((char*)d_ws + 524288);                // 2048 B
  float* y2p  = (float*)((char*)d_ws + 524288 + 2048);         // 4 B

  bias_expmap_k<<<dim3(1), dim3(512), 0, stream>>>(bias, bexp, y2p);
  pack_weight_k<<<dim3(1024), dim3(256), 0, stream>>>(w, wsB);

  // 131072 rows / 16 rows-per-wave = 8192 waves = 2048 blocks x 4 waves
  hyp_free_k<<<dim3(2048), dim3(256), 0, stream>>>(x, wsB, bexp, y2p, out);
}